// Round 9
// baseline (329.170 us; speedup 1.0000x reference)
//
#include <hip/hip_runtime.h>
#include <math.h>

// Problem constants
// x: (16, 3, 512, 512) fp32; weights tiny; out: 4 fp32 scalars
constexpr int TH = 16, TW = 64;          // output tile per block
constexpr int LH = TH + 4, LW = TW + 8;  // yuv tile with halo (top 4, left 4, right 4)

__device__ __forceinline__ float leaky(float v){ return v >= 0.0f ? v : 0.01f * v; }

__global__ void codec_zero(unsigned int* ws, int n){
  int i = blockIdx.x * 256 + threadIdx.x;
  if (i < n) ws[i] = 0u;
}

__global__ __launch_bounds__(256) void codec_main(
    const float* __restrict__ x,
    const float* __restrict__ w0T, const float* __restrict__ w0L,
    const float* __restrict__ b0L,
    const float* __restrict__ w1, const float* __restrict__ b1,
    const float* __restrict__ w2, const float* __restrict__ b2,
    unsigned int* __restrict__ histX, unsigned int* __restrict__ histD,
    float* __restrict__ sums)
{
  __shared__ float yuv[3][LH][LW];
  __shared__ unsigned int lhX[3][256];
  __shared__ unsigned int lhD[3][256];
  __shared__ float red[2];

  const int tid = threadIdx.x;
  const int b  = blockIdx.z;
  const int h0 = blockIdx.y * TH;
  const int w0 = blockIdx.x * TW;

  for (int i = tid; i < 3*256; i += 256){ (&lhX[0][0])[i] = 0u; (&lhD[0][0])[i] = 0u; }
  if (tid < 2) red[tid] = 0.0f;

  // ---- load x tile (+halo) -> yuv in LDS; zero outside image (matches jnp.pad) ----
  const float* xb = x + (size_t)b * (3*512*512);
  for (int i = tid; i < LH*LW; i += 256){
    int lr = i / LW, lc = i % LW;
    int h = h0 + lr - 4, w = w0 + lc - 4;
    float r = 0.f, g = 0.f, bb = 0.f;
    if (h >= 0 && w >= 0 && w < 512){   // h < 512 always (h0 <= 496, lr <= 19)
      int off = h*512 + w;
      r  = xb[off];
      g  = xb[262144 + off];
      bb = xb[524288 + off];
    }
    yuv[0][lr][lc] = r - g;
    yuv[1][lr][lc] = g;
    yuv[2][lr][lc] = bb - g;
  }
  __syncthreads();

  const int tx  = tid & 63;   // column within tile
  const int tyg = tid >> 6;   // 4-row group: rows tyg*4 .. tyg*4+3

  // ---- conv0T: 12 oc, 3 ic, 4x9 causal-top window ----
  float acc[4][12];
  #pragma unroll
  for (int p = 0; p < 4; ++p)
    #pragma unroll
    for (int oc = 0; oc < 12; ++oc) acc[p][oc] = 0.0f;

  for (int r = 0; r < 7; ++r){            // union of the 4 pixels' context rows
    #pragma unroll
    for (int ic = 0; ic < 3; ++ic){
      float row[9];
      #pragma unroll
      for (int dx = 0; dx < 9; ++dx) row[dx] = yuv[ic][tyg*4 + r][tx + dx];
      #pragma unroll
      for (int p = 0; p < 4; ++p){
        int dy = r - p;                   // context row index within the 4x9 kernel
        if (dy >= 0 && dy < 4){
          #pragma unroll
          for (int oc = 0; oc < 12; ++oc){
            const float* wq = w0T + oc*108 + ic*36 + dy*9; // ((oc*3+ic)*4+dy)*9
            #pragma unroll
            for (int dx = 0; dx < 9; ++dx)
              acc[p][oc] = fmaf(wq[dx], row[dx], acc[p][oc]);
          }
        }
      }
    }
  }

  float lsq_d = 0.0f, lsq_x = 0.0f;

  #pragma unroll
  for (int p = 0; p < 4; ++p){
    const int lr = tyg*4 + 4 + p;         // pixel row in LDS coords
    // conv0L (4 left neighbors) + bias
    float h0v[12];
    #pragma unroll
    for (int oc = 0; oc < 12; ++oc) h0v[oc] = acc[p][oc] + b0L[oc];
    #pragma unroll
    for (int ic = 0; ic < 3; ++ic){
      float l0 = yuv[ic][lr][tx+0], l1 = yuv[ic][lr][tx+1];
      float l2 = yuv[ic][lr][tx+2], l3 = yuv[ic][lr][tx+3];
      #pragma unroll
      for (int oc = 0; oc < 12; ++oc){
        const float* wq = w0L + (oc*3+ic)*4;
        h0v[oc] = fmaf(wq[0], l0, fmaf(wq[1], l1, fmaf(wq[2], l2, fmaf(wq[3], l3, h0v[oc]))));
      }
    }
    #pragma unroll
    for (int oc = 0; oc < 12; ++oc) h0v[oc] = leaky(h0v[oc]);

    // conv1 (grouped 1x1, 4->4 per group) + leaky
    float h1v[12];
    #pragma unroll
    for (int j = 0; j < 12; ++j){
      int gsel = (j >> 2) << 2;
      float s = b1[j];
      #pragma unroll
      for (int k = 0; k < 4; ++k) s = fmaf(w1[j*4+k], h0v[gsel+k], s);
      h1v[j] = leaky(s);
    }
    // conv2 (grouped 1x1, 4->1 per group)
    float pr2[3];
    #pragma unroll
    for (int c = 0; c < 3; ++c){
      float s = b2[c];
      #pragma unroll
      for (int k = 0; k < 4; ++k) s = fmaf(w2[c*4+k], h1v[c*4+k], s);
      pr2[c] = s;
    }

    const int lc  = tx + 4;
    const float gpix = yuv[1][lr][lc];    // exact g at (h,w)
    const int h = h0 + tyg*4 + p;
    const int w = w0 + tx;
    const int off = h*512 + w;

    #pragma unroll
    for (int c = 0; c < 3; ++c){
      // median3(pred, vmin, vmax) == clamp(pred, vmin, vmax)
      float n  = yuv[c][lr-1][lc];
      float wv = yuv[c][lr][lc-1];
      float ne = yuv[c][lr-1][lc+1];
      float vmin = fminf(wv, fminf(n, ne));
      float vmax = fmaxf(wv, fmaxf(n, ne));
      float pv = fminf(fmaxf(pr2[c], vmin), vmax);
      pv = (c == 1) ? pv : pv + gpix;     // back to RGB-ish space
      pv = fminf(fmaxf(pv, -1.0f), 1.0f);

      float xv = xb[c*262144 + off];
      float d  = xv - pv;
      lsq_d = fmaf(d, d, lsq_d);
      lsq_x = fmaf(xv, xv, lsq_x);

      // histogram of x
      int ix = (int)floorf((xv + 1.0f) * 128.0f);
      ix = ix < 0 ? 0 : (ix > 255 ? 255 : ix);
      if (xv >= -1.0f && xv <= 1.0f) atomicAdd(&lhX[c][ix], 1u);

      // histogram of wrapped delta
      float wd = fmodf(d + 1.0f, 2.0f) - 1.0f;
      int id = (int)floorf((wd + 1.0f) * 128.0f);
      id = id < 0 ? 0 : (id > 255 ? 255 : id);
      if (wd >= -1.0f && wd <= 1.0f) atomicAdd(&lhD[c][id], 1u);
    }
  }

  // ---- reductions ----
  #pragma unroll
  for (int s = 32; s > 0; s >>= 1){
    lsq_d += __shfl_down(lsq_d, s);
    lsq_x += __shfl_down(lsq_x, s);
  }
  if ((tid & 63) == 0){ atomicAdd(&red[0], lsq_d); atomicAdd(&red[1], lsq_x); }
  __syncthreads();
  if (tid == 0){ atomicAdd(&sums[0], red[0]); atomicAdd(&sums[1], red[1]); }

  // flush per-block histograms
  for (int i = tid; i < 3*256; i += 256){
    int c = i >> 8, bin = i & 255;
    unsigned vX = lhX[c][bin];
    if (vX) atomicAdd(&histX[(b*3 + c)*256 + bin], vX);
    unsigned vD = lhD[c][bin];
    if (vD) atomicAdd(&histD[(b*3 + c)*256 + bin], vD);
  }
}

__global__ __launch_bounds__(256) void codec_final(
    const unsigned int* __restrict__ histX,
    const unsigned int* __restrict__ histD,
    const float* __restrict__ sums,
    float* __restrict__ out)
{
  __shared__ float se[2];
  if (threadIdx.x < 2) se[threadIdx.x] = 0.0f;
  __syncthreads();
  float eX = 0.0f, eD = 0.0f;
  for (int i = threadIdx.x; i < 48*256; i += 256){
    float pX = (float)histX[i] * (1.0f/262144.0f);
    if (pX > 0.0f) eX -= pX * log2f(pX);
    float pD = (float)histD[i] * (1.0f/262144.0f);
    if (pD > 0.0f) eD -= pD * log2f(pD);
  }
  #pragma unroll
  for (int s = 32; s > 0; s >>= 1){
    eX += __shfl_down(eX, s);
    eD += __shfl_down(eD, s);
  }
  if ((threadIdx.x & 63) == 0){ atomicAdd(&se[0], eX); atomicAdd(&se[1], eD); }
  __syncthreads();
  if (threadIdx.x == 0){
    out[0] = 255.0f * sqrtf(sums[0] * (1.0f/12582912.0f)); // loss1
    out[1] = 255.0f * sqrtf(sums[1] * (1.0f/12582912.0f)); // loss0
    out[2] = se[0] * (1.0f/384.0f);                        // invCR0  (ent/(8*48))
    out[3] = se[1] * (1.0f/384.0f);                        // invCR1
  }
}

extern "C" void kernel_launch(void* const* d_in, const int* in_sizes, int n_in,
                              void* d_out, int out_size, void* d_ws, size_t ws_size,
                              hipStream_t stream) {
  const float* x   = (const float*)d_in[0];
  const float* w0T = (const float*)d_in[1];
  const float* w0L = (const float*)d_in[2];
  const float* b0L = (const float*)d_in[3];
  const float* w1  = (const float*)d_in[4];
  const float* b1  = (const float*)d_in[5];
  const float* w2  = (const float*)d_in[6];
  const float* b2  = (const float*)d_in[7];

  unsigned int* histX = (unsigned int*)d_ws;            // 48*256
  unsigned int* histD = histX + 48*256;                 // 48*256
  float* sums = (float*)(histD + 48*256);               // [sumsq_delta, sumsq_x]
  float* out = (float*)d_out;

  const int nzero = 48*256*2 + 2;
  codec_zero<<<(nzero + 255)/256, 256, 0, stream>>>((unsigned int*)d_ws, nzero);

  dim3 grid(512/TW, 512/TH, 16);
  codec_main<<<grid, 256, 0, stream>>>(x, w0T, w0L, b0L, w1, b1, w2, b2,
                                       histX, histD, sums);
  codec_final<<<1, 256, 0, stream>>>(histX, histD, sums, out);
}

// Round 12
// 239.278 us; speedup vs baseline: 1.3757x; 1.3757x over previous
//
#include <hip/hip_runtime.h>
#include <math.h>

// x: (16, 3, 512, 512) fp32; weights tiny; out: 4 fp32 scalars
constexpr int TH = 16, TW = 64;          // output tile per block
constexpr int LH = TH + 4, LW = TW + 8;  // yuv tile with halo (top 4, left 4, right 4)

typedef __attribute__((ext_vector_type(8))) short bf16x8;   // 8 bf16 = 4 VGPRs (MFMA A/B frag)
typedef __attribute__((ext_vector_type(4))) float f32x4;    // MFMA C/D frag

__device__ __forceinline__ float leaky(float v){ return v >= 0.0f ? v : 0.01f * v; }

// pack 2 fp32 -> 2 bf16 (RNE). No builtin on gfx950 (learn_hip m240) -> inline asm.
__device__ __forceinline__ unsigned cvt_pk_bf16(float lo, float hi){
  unsigned r;
  asm("v_cvt_pk_bf16_f32 %0, %1, %2" : "=v"(r) : "v"(lo), "v"(hi));
  return r;
}

__global__ void codec_zero(unsigned int* ws, int n){
  int i = blockIdx.x * 256 + threadIdx.x;
  if (i < n) ws[i] = 0u;
}

__global__ __launch_bounds__(256) void codec_main(
    const float* __restrict__ x,
    const float* __restrict__ w0T, const float* __restrict__ w0L,
    const float* __restrict__ b0L,
    const float* __restrict__ w1, const float* __restrict__ b1,
    const float* __restrict__ w2, const float* __restrict__ b2,
    unsigned int* __restrict__ histX, unsigned int* __restrict__ histD,
    float* __restrict__ sums)
{
  __shared__ float yuv[3][LH][LW];                                   // 17280 B
  __shared__ __attribute__((aligned(16))) float h0buf[4][4][16][16]; // wave,strip,px,oc: 16384 B
  __shared__ unsigned int lhX[3][256];
  __shared__ unsigned int lhD[3][256];
  __shared__ float red[2];

  const int tid  = threadIdx.x;
  const int lane = tid & 63;
  const int wv   = tid >> 6;      // wave id 0..3
  const int p    = lane & 15;     // A: oc row | B: pixel col | D: pixel col
  const int g    = lane >> 4;     // k-group 0..3

  const int b  = blockIdx.z;
  const int h0 = blockIdx.y * TH;
  const int w0 = blockIdx.x * TW;

  // ---- A fragments (weights), built once per thread -------------------------
  // K-permutation (group G = t*4+g, element e=0..7):
  //   G<12 (t<3): ic=t, dy=g, dx=e            -> w0T[oc][ic][dy][e]
  //   G=12..14 (t=3, g=ic<3): e<4: left j=e   -> w0L[oc][ic][0][e]
  //                           e>=4: dy=e-4,dx=8 -> w0T[oc][ic][e-4][8]
  //   G=15: zero pad. oc>=12: zero rows.
  bf16x8 afrag[4];
  #pragma unroll
  for (int t = 0; t < 4; ++t){
    float wv8[8];
    #pragma unroll
    for (int e = 0; e < 8; ++e){
      float v = 0.0f;
      if (p < 12){
        if (t < 3)          v = w0T[p*108 + t*36 + g*9 + e];
        else if (g < 3)     v = (e < 4) ? w0L[p*12 + g*4 + e]
                                        : w0T[p*108 + g*36 + (e-4)*9 + 8];
      }
      wv8[e] = v;
    }
    union { unsigned u[4]; bf16x8 s; } pk;
    #pragma unroll
    for (int i = 0; i < 4; ++i) pk.u[i] = cvt_pk_bf16(wv8[2*i], wv8[2*i+1]);
    afrag[t] = pk.s;
  }

  for (int i = tid; i < 3*256; i += 256){ (&lhX[0][0])[i] = 0u; (&lhD[0][0])[i] = 0u; }
  if (tid < 2) red[tid] = 0.0f;

  // ---- load x tile (+halo) -> yuv in LDS; zero outside image (matches jnp.pad)
  const float* xb = x + (size_t)b * (3*512*512);
  for (int i = tid; i < LH*LW; i += 256){
    int lr = i / LW, lc = i % LW;
    int h = h0 + lr - 4, w = w0 + lc - 4;
    float r = 0.f, gg = 0.f, bb = 0.f;
    if (h >= 0 && w >= 0 && w < 512){
      int off = h*512 + w;
      r  = xb[off];
      gg = xb[262144 + off];
      bb = xb[524288 + off];
    }
    yuv[0][lr][lc] = r - gg;
    yuv[1][lr][lc] = gg;
    yuv[2][lr][lc] = bb - gg;
  }
  __syncthreads();

  float lsq_d = 0.0f, lsq_x = 0.0f;

  // wave wv owns output rows wv*4 .. wv*4+3; per row: 4 GEMM strips of 16 px,
  // then 64-lane-parallel epilogue (1 px/lane).
  for (int qi = 0; qi < 4; ++qi){
    const int row = wv*4 + qi;
    const int lr  = row + 4;          // LDS row of the output pixel

    for (int s = 0; s < 4; ++s){
      const int lc = 4 + s*16 + p;    // LDS col of this lane's pixel
      f32x4 acc = {0.f, 0.f, 0.f, 0.f};
      #pragma unroll
      for (int t = 0; t < 4; ++t){
        float f[8];
        if (t < 3){
          const float* src = &yuv[t][lr-4+g][lc-4];
          #pragma unroll
          for (int i = 0; i < 8; ++i) f[i] = src[i];
        } else {
          const int ic = (g < 3) ? g : 2;      // g==3 -> pad group (A rows are 0)
          const float* L = &yuv[ic][lr][lc-4];
          #pragma unroll
          for (int i = 0; i < 4; ++i) f[i] = L[i];
          #pragma unroll
          for (int dy = 0; dy < 4; ++dy) f[4+dy] = yuv[ic][lr-4+dy][lc+4];
        }
        union { unsigned u[4]; bf16x8 s_; } pk;
        #pragma unroll
        for (int i = 0; i < 4; ++i) pk.u[i] = cvt_pk_bf16(f[2*i], f[2*i+1]);
        acc = __builtin_amdgcn_mfma_f32_16x16x32_bf16(afrag[t], pk.s_, acc, 0, 0, 0);
      }
      // D: col=lane&15 (pixel), row=(lane>>4)*4+reg (oc). g=3 writes oc12..15 pad.
      *(f32x4*)&h0buf[wv][s][p][g*4] = acc;
    }

    // ---- epilogue: lane -> pixel column `lane` of this row --------------------
    const int colp = lane;
    const int lc2  = colp + 4;
    f32x4 r0 = *(const f32x4*)&h0buf[wv][colp>>4][colp&15][0];
    f32x4 r1 = *(const f32x4*)&h0buf[wv][colp>>4][colp&15][4];
    f32x4 r2 = *(const f32x4*)&h0buf[wv][colp>>4][colp&15][8];
    float h0v[12] = { r0[0], r0[1], r0[2], r0[3],
                      r1[0], r1[1], r1[2], r1[3],
                      r2[0], r2[1], r2[2], r2[3] };
    #pragma unroll
    for (int oc = 0; oc < 12; ++oc) h0v[oc] = leaky(h0v[oc] + b0L[oc]);

    float h1v[12];
    #pragma unroll
    for (int j = 0; j < 12; ++j){
      int gsel = (j >> 2) << 2;
      float sv = b1[j];
      #pragma unroll
      for (int k = 0; k < 4; ++k) sv = fmaf(w1[j*4+k], h0v[gsel+k], sv);
      h1v[j] = leaky(sv);
    }
    float pr2[3];
    #pragma unroll
    for (int c = 0; c < 3; ++c){
      float sv = b2[c];
      #pragma unroll
      for (int k = 0; k < 4; ++k) sv = fmaf(w2[c*4+k], h1v[c*4+k], sv);
      pr2[c] = sv;
    }

    const float gpix = yuv[1][lr][lc2];
    const int h = h0 + row;
    const int w = w0 + colp;
    const int off = h*512 + w;

    #pragma unroll
    for (int c = 0; c < 3; ++c){
      float n  = yuv[c][lr-1][lc2];
      float wl = yuv[c][lr][lc2-1];
      float ne = yuv[c][lr-1][lc2+1];
      float vmin = fminf(wl, fminf(n, ne));
      float vmax = fmaxf(wl, fmaxf(n, ne));
      float pv = fminf(fmaxf(pr2[c], vmin), vmax);
      pv = (c == 1) ? pv : pv + gpix;
      pv = fminf(fmaxf(pv, -1.0f), 1.0f);

      float xv = xb[c*262144 + off];
      float d  = xv - pv;
      lsq_d = fmaf(d, d, lsq_d);
      lsq_x = fmaf(xv, xv, lsq_x);

      int ix = (int)floorf((xv + 1.0f) * 128.0f);
      ix = ix < 0 ? 0 : (ix > 255 ? 255 : ix);
      if (xv >= -1.0f && xv <= 1.0f) atomicAdd(&lhX[c][ix], 1u);

      float wd = fmodf(d + 1.0f, 2.0f) - 1.0f;
      int id = (int)floorf((wd + 1.0f) * 128.0f);
      id = id < 0 ? 0 : (id > 255 ? 255 : id);
      if (wd >= -1.0f && wd <= 1.0f) atomicAdd(&lhD[c][id], 1u);
    }
  }

  // ---- reductions ----
  #pragma unroll
  for (int sft = 32; sft > 0; sft >>= 1){
    lsq_d += __shfl_down(lsq_d, sft);
    lsq_x += __shfl_down(lsq_x, sft);
  }
  if ((tid & 63) == 0){ atomicAdd(&red[0], lsq_d); atomicAdd(&red[1], lsq_x); }
  __syncthreads();
  if (tid == 0){ atomicAdd(&sums[0], red[0]); atomicAdd(&sums[1], red[1]); }

  for (int i = tid; i < 3*256; i += 256){
    int c = i >> 8, bin = i & 255;
    unsigned vX = lhX[c][bin];
    if (vX) atomicAdd(&histX[(b*3 + c)*256 + bin], vX);
    unsigned vD = lhD[c][bin];
    if (vD) atomicAdd(&histD[(b*3 + c)*256 + bin], vD);
  }
}

__global__ __launch_bounds__(256) void codec_final(
    const unsigned int* __restrict__ histX,
    const unsigned int* __restrict__ histD,
    const float* __restrict__ sums,
    float* __restrict__ out)
{
  __shared__ float se[2];
  if (threadIdx.x < 2) se[threadIdx.x] = 0.0f;
  __syncthreads();
  float eX = 0.0f, eD = 0.0f;
  for (int i = threadIdx.x; i < 48*256; i += 256){
    float pX = (float)histX[i] * (1.0f/262144.0f);
    if (pX > 0.0f) eX -= pX * log2f(pX);
    float pD = (float)histD[i] * (1.0f/262144.0f);
    if (pD > 0.0f) eD -= pD * log2f(pD);
  }
  #pragma unroll
  for (int s = 32; s > 0; s >>= 1){
    eX += __shfl_down(eX, s);
    eD += __shfl_down(eD, s);
  }
  if ((threadIdx.x & 63) == 0){ atomicAdd(&se[0], eX); atomicAdd(&se[1], eD); }
  __syncthreads();
  if (threadIdx.x == 0){
    out[0] = 255.0f * sqrtf(sums[0] * (1.0f/12582912.0f)); // loss1
    out[1] = 255.0f * sqrtf(sums[1] * (1.0f/12582912.0f)); // loss0
    out[2] = se[0] * (1.0f/384.0f);                        // invCR0
    out[3] = se[1] * (1.0f/384.0f);                        // invCR1
  }
}

extern "C" void kernel_launch(void* const* d_in, const int* in_sizes, int n_in,
                              void* d_out, int out_size, void* d_ws, size_t ws_size,
                              hipStream_t stream) {
  const float* x   = (const float*)d_in[0];
  const float* w0T = (const float*)d_in[1];
  const float* w0L = (const float*)d_in[2];
  const float* b0L = (const float*)d_in[3];
  const float* w1  = (const float*)d_in[4];
  const float* b1  = (const float*)d_in[5];
  const float* w2  = (const float*)d_in[6];
  const float* b2  = (const float*)d_in[7];

  unsigned int* histX = (unsigned int*)d_ws;            // 48*256
  unsigned int* histD = histX + 48*256;                 // 48*256
  float* sums = (float*)(histD + 48*256);               // [sumsq_delta, sumsq_x]
  float* out = (float*)d_out;

  const int nzero = 48*256*2 + 2;
  codec_zero<<<(nzero + 255)/256, 256, 0, stream>>>((unsigned int*)d_ws, nzero);

  dim3 grid(512/TW, 512/TH, 16);
  codec_main<<<grid, 256, 0, stream>>>(x, w0T, w0L, b0L, w1, b1, w2, b2,
                                       histX, histD, sums);
  codec_final<<<1, 256, 0, stream>>>(histX, histD, sums, out);
}

// Round 14
// 238.389 us; speedup vs baseline: 1.3808x; 1.0037x over previous
//
#include <hip/hip_runtime.h>
#include <math.h>

// x: (16, 3, 512, 512) fp32; weights tiny; out: 4 fp32 scalars
constexpr int TH = 16, TW = 64;            // output tile per block
constexpr int LH = TH + 4, LW = TW + 8;    // 20 x 72 fp32 yuv tile (halo 4)
constexpr int PLS = LH*LW + 8;             // fp32 plane stride 1448 (mod 32 = 8: de-conflicts planes)
constexpr int PKW = LW/2;                  // 36 packed words per row
constexpr int PKPL = LH*PKW;               // 720 words per plane
constexpr int PKPAR = 3*PKPL;              // 2160 words per parity copy (mod 32 = 16)

typedef __attribute__((ext_vector_type(8))) short bf16x8;
typedef __attribute__((ext_vector_type(4))) float f32x4;

__device__ __forceinline__ float leaky(float v){ return v >= 0.0f ? v : 0.01f * v; }

__device__ __forceinline__ unsigned cvt_pk_bf16(float lo, float hi){
  unsigned r;
  asm("v_cvt_pk_bf16_f32 %0, %1, %2" : "=v"(r) : "v"(lo), "v"(hi));
  return r;
}

__global__ void codec_zero(unsigned int* ws, int n){
  int i = blockIdx.x * 256 + threadIdx.x;
  if (i < n) ws[i] = 0u;
}

__global__ __launch_bounds__(256) void codec_main(
    const float* __restrict__ x,
    const float* __restrict__ w0T, const float* __restrict__ w0L,
    const float* __restrict__ b0L,
    const float* __restrict__ w1, const float* __restrict__ b1,
    const float* __restrict__ w2, const float* __restrict__ b2,
    unsigned int* __restrict__ histX, unsigned int* __restrict__ histD,
    float* __restrict__ sums)
{
  __shared__ float yuvF[3*PLS];              // 17376 B fp32 (epilogue exactness)
  __shared__ unsigned pkF[2*PKPAR];          // 17280 B dual-parity bf16 pairs (GEMM)
  __shared__ unsigned int lhX[3][256];
  __shared__ unsigned int lhD[3][256];
  __shared__ float red[2];

  const int tid  = threadIdx.x;
  const int lane = tid & 63;
  const int wv   = tid >> 6;      // wave 0..3
  const int p    = lane & 15;     // A: oc row | B/D: pixel col
  const int g    = lane >> 4;     // k-group / D oc-group / epilogue channel
  const int gg   = (g < 3) ? g : 0;  // clamped for weight loads (g=3 lanes idle in epilogue)

  const int b  = blockIdx.z;
  const int h0 = blockIdx.y * TH;
  const int w0 = blockIdx.x * TW;

#define YUV(t, r, c) yuvF[(t)*PLS + (r)*LW + (c)]

  // ---- A fragments (weights) — unchanged from verified round-12 kernel ------
  // K-permutation (group G = t*4+g, element e): G<12: w0T[oc][t][g][e];
  // G=12..14: e<4 -> w0L[oc][g][0][e], e>=4 -> w0T[oc][g][e-4][8]; G=15 + oc>=12: zero.
  bf16x8 afrag[4];
  #pragma unroll
  for (int t = 0; t < 4; ++t){
    float wv8[8];
    #pragma unroll
    for (int e = 0; e < 8; ++e){
      float v = 0.0f;
      if (p < 12){
        if (t < 3)          v = w0T[p*108 + t*36 + g*9 + e];
        else if (g < 3)     v = (e < 4) ? w0L[p*12 + g*4 + e]
                                        : w0T[p*108 + g*36 + (e-4)*9 + 8];
      }
      wv8[e] = v;
    }
    union { unsigned u[4]; bf16x8 s; } pk;
    #pragma unroll
    for (int i = 0; i < 4; ++i) pk.u[i] = cvt_pk_bf16(wv8[2*i], wv8[2*i+1]);
    afrag[t] = pk.s;
  }

  // ---- hoisted epilogue weights (per-lane group gg) --------------------------
  float b0g[4], b1g[4], w2g[4], w1g[4][4];
  #pragma unroll
  for (int k = 0; k < 4; ++k){
    b0g[k] = b0L[4*gg + k];
    b1g[k] = b1[4*gg + k];
    w2g[k] = w2[gg*4 + k];
  }
  #pragma unroll
  for (int jj = 0; jj < 4; ++jj)
    #pragma unroll
    for (int k = 0; k < 4; ++k) w1g[jj][k] = w1[(4*gg + jj)*4 + k];
  const float b2g = b2[gg];

  for (int i = tid; i < 3*256; i += 256){ (&lhX[0][0])[i] = 0u; (&lhD[0][0])[i] = 0u; }
  if (tid < 2) red[tid] = 0.0f;

  // ---- stage fp32 yuv tile (+halo), zero outside image -----------------------
  const float* xb = x + (size_t)b * (3*512*512);
  for (int i = tid; i < LH*LW; i += 256){
    int lr = i / LW, lc = i % LW;
    int h = h0 + lr - 4, w = w0 + lc - 4;
    float r = 0.f, ggv = 0.f, bb = 0.f;
    if (h >= 0 && w >= 0 && w < 512){
      int off = h*512 + w;
      r   = xb[off];
      ggv = xb[262144 + off];
      bb  = xb[524288 + off];
    }
    YUV(0, lr, lc) = r - ggv;
    YUV(1, lr, lc) = ggv;
    YUV(2, lr, lc) = bb - ggv;
  }
  __syncthreads();

  // ---- stage dual-parity bf16 packed copies (bit-identical RNE to cvt in GEMM)
  for (int i = tid; i < 2*PKPAR; i += 256){
    int par = i / PKPAR, rem = i % PKPAR;
    int pl = rem / PKPL, r2 = (rem % PKPL) / PKW, wd = rem % PKW;
    int c0 = 2*wd + par, c1 = c0 + 1;
    float lo = YUV(pl, r2, c0);                       // c0 <= 71 always
    float hi = (c1 < LW) ? YUV(pl, r2, c1) : 0.0f;    // parity-1 word 35 pads 0
    pkF[i] = cvt_pk_bf16(lo, hi);
  }
  __syncthreads();

  float lsq_d = 0.0f, lsq_x = 0.0f;

  // wave wv owns rows wv*4..wv*4+3; per row, 4 strips of 16 px; epilogue is
  // in-register: lane (p,g) -> pixel p of strip, channel c=g (g=3 idle).
  for (int qi = 0; qi < 4; ++qi){
    const int row = wv*4 + qi;
    const int lr  = row + 4;

    for (int s = 0; s < 4; ++s){
      const int c0    = s*16 + p;          // leftmost context col (= pixel col in tile coords)
      const int par   = c0 & 1;
      const int wbase = (c0 - par) >> 1;
      f32x4 acc = {0.f, 0.f, 0.f, 0.f};

      #pragma unroll
      for (int t = 0; t < 4; ++t){
        union { unsigned u[4]; bf16x8 v; } B;
        if (t < 3){
          const unsigned* src = &pkF[par*PKPAR + t*PKPL + (lr-4+g)*PKW + wbase];
          #pragma unroll
          for (int i = 0; i < 4; ++i) B.u[i] = src[i];
        } else {
          const int ic = (g < 3) ? g : 2;  // g=3: A column is zero, value irrelevant
          const unsigned* L = &pkF[par*PKPAR + ic*PKPL + lr*PKW + wbase];
          B.u[0] = L[0]; B.u[1] = L[1];
          float f4 = YUV(ic, lr-4+0, c0+8);
          float f5 = YUV(ic, lr-4+1, c0+8);
          float f6 = YUV(ic, lr-4+2, c0+8);
          float f7 = YUV(ic, lr-4+3, c0+8);
          B.u[2] = cvt_pk_bf16(f4, f5);
          B.u[3] = cvt_pk_bf16(f6, f7);
        }
        acc = __builtin_amdgcn_mfma_f32_16x16x32_bf16(afrag[t], B.v, acc, 0, 0, 0);
      }

      // ---- in-register epilogue: D gives lane (p,g) h0[oc=4g+k] of pixel p --
      if (g < 3){
        const int lc = c0 + 4;
        float h0v[4], h1v[4];
        #pragma unroll
        for (int k = 0; k < 4; ++k) h0v[k] = leaky(acc[k] + b0g[k]);
        #pragma unroll
        for (int jj = 0; jj < 4; ++jj){
          float sv = b1g[jj];
          #pragma unroll
          for (int k = 0; k < 4; ++k) sv = fmaf(w1g[jj][k], h0v[k], sv);
          h1v[jj] = leaky(sv);
        }
        float pr = b2g;
        #pragma unroll
        for (int k = 0; k < 4; ++k) pr = fmaf(w2g[k], h1v[k], pr);

        float n  = YUV(g, lr-1, lc);
        float wl = YUV(g, lr,   lc-1);
        float ne = YUV(g, lr-1, lc+1);
        float vmin = fminf(wl, fminf(n, ne));
        float vmax = fmaxf(wl, fmaxf(n, ne));
        float pv = fminf(fmaxf(pr, vmin), vmax);
        float gpix = YUV(1, lr, lc);
        pv = (g == 1) ? pv : pv + gpix;
        pv = fminf(fmaxf(pv, -1.0f), 1.0f);

        float xv = xb[g*262144 + (h0+row)*512 + (w0 + s*16 + p)];
        float d  = xv - pv;
        lsq_d = fmaf(d, d, lsq_d);
        lsq_x = fmaf(xv, xv, lsq_x);

        int ix = (int)floorf((xv + 1.0f) * 128.0f);
        ix = ix < 0 ? 0 : (ix > 255 ? 255 : ix);
        if (xv >= -1.0f && xv <= 1.0f) atomicAdd(&lhX[g][ix], 1u);

        float wd2 = fmodf(d + 1.0f, 2.0f) - 1.0f;
        int id = (int)floorf((wd2 + 1.0f) * 128.0f);
        id = id < 0 ? 0 : (id > 255 ? 255 : id);
        if (wd2 >= -1.0f && wd2 <= 1.0f) atomicAdd(&lhD[g][id], 1u);
      }
    }
  }

  // ---- reductions ----
  #pragma unroll
  for (int sft = 32; sft > 0; sft >>= 1){
    lsq_d += __shfl_down(lsq_d, sft);
    lsq_x += __shfl_down(lsq_x, sft);
  }
  if ((tid & 63) == 0){ atomicAdd(&red[0], lsq_d); atomicAdd(&red[1], lsq_x); }
  __syncthreads();
  if (tid == 0){ atomicAdd(&sums[0], red[0]); atomicAdd(&sums[1], red[1]); }

  for (int i = tid; i < 3*256; i += 256){
    int c = i >> 8, bin = i & 255;
    unsigned vX = lhX[c][bin];
    if (vX) atomicAdd(&histX[(b*3 + c)*256 + bin], vX);
    unsigned vD = lhD[c][bin];
    if (vD) atomicAdd(&histD[(b*3 + c)*256 + bin], vD);
  }
#undef YUV
}

__global__ __launch_bounds__(256) void codec_final(
    const unsigned int* __restrict__ histX,
    const unsigned int* __restrict__ histD,
    const float* __restrict__ sums,
    float* __restrict__ out)
{
  __shared__ float se[2];
  if (threadIdx.x < 2) se[threadIdx.x] = 0.0f;
  __syncthreads();
  float eX = 0.0f, eD = 0.0f;
  for (int i = threadIdx.x; i < 48*256; i += 256){
    float pX = (float)histX[i] * (1.0f/262144.0f);
    if (pX > 0.0f) eX -= pX * log2f(pX);
    float pD = (float)histD[i] * (1.0f/262144.0f);
    if (pD > 0.0f) eD -= pD * log2f(pD);
  }
  #pragma unroll
  for (int s = 32; s > 0; s >>= 1){
    eX += __shfl_down(eX, s);
    eD += __shfl_down(eD, s);
  }
  if ((threadIdx.x & 63) == 0){ atomicAdd(&se[0], eX); atomicAdd(&se[1], eD); }
  __syncthreads();
  if (threadIdx.x == 0){
    out[0] = 255.0f * sqrtf(sums[0] * (1.0f/12582912.0f)); // loss1
    out[1] = 255.0f * sqrtf(sums[1] * (1.0f/12582912.0f)); // loss0
    out[2] = se[0] * (1.0f/384.0f);                        // invCR0
    out[3] = se[1] * (1.0f/384.0f);                        // invCR1
  }
}

extern "C" void kernel_launch(void* const* d_in, const int* in_sizes, int n_in,
                              void* d_out, int out_size, void* d_ws, size_t ws_size,
                              hipStream_t stream) {
  const float* x   = (const float*)d_in[0];
  const float* w0T = (const float*)d_in[1];
  const float* w0L = (const float*)d_in[2];
  const float* b0L = (const float*)d_in[3];
  const float* w1  = (const float*)d_in[4];
  const float* b1  = (const float*)d_in[5];
  const float* w2  = (const float*)d_in[6];
  const float* b2  = (const float*)d_in[7];

  unsigned int* histX = (unsigned int*)d_ws;            // 48*256
  unsigned int* histD = histX + 48*256;                 // 48*256
  float* sums = (float*)(histD + 48*256);               // [sumsq_delta, sumsq_x]
  float* out = (float*)d_out;

  const int nzero = 48*256*2 + 2;
  codec_zero<<<(nzero + 255)/256, 256, 0, stream>>>((unsigned int*)d_ws, nzero);

  dim3 grid(512/TW, 512/TH, 16);
  codec_main<<<grid, 256, 0, stream>>>(x, w0T, w0L, b0L, w1, b1, w2, b2,
                                       histX, histD, sums);
  codec_final<<<1, 256, 0, stream>>>(histX, histD, sums, out);
}